// Round 4
// baseline (526.213 us; speedup 1.0000x reference)
//
#include <hip/hip_runtime.h>
#include <cstdint>
#include <cstddef>

#define NB 32
#define NN 1024
#define ND 256
#define KNNK 16

// ---------------------------------------------------------------------------
// Kernel A v3: fused positional-add + dual projection GEMM, TRANSPOSED out:
//   Qt [B, 256, 1024], Kt [B, 256, 1024]   (out[e][n] = sum_d h[n][d] w[e][d])
// Tile: 64 e x 64 n, 256 threads, 4x4 microtile. (measured ~90 us)
// ---------------------------------------------------------------------------
__global__ __launch_bounds__(256) void proj_kernel(
    const float* __restrict__ x, const float* __restrict__ pos,
    const float* __restrict__ wq, const float* __restrict__ bq,
    const float* __restrict__ wk, const float* __restrict__ bk,
    float* __restrict__ Qt, float* __restrict__ Kt)
{
    __shared__ __align__(16) float Hs[16][64];   // [d][n_local]
    __shared__ __align__(16) float Ws[16][64];   // [d][e_local]

    const int tid = threadIdx.x;
    const int tx = tid & 15;          // n microtile index
    const int ty = tid >> 4;          // e microtile index
    const int bm = blockIdx.x >> 3;   // 0..511 n tiles (b*16 + ntile)
    const int be = blockIdx.x & 7;    // 0..7 e tiles (0-3 -> Q, 4-7 -> K)
    const int nBase = bm << 6;        // global flattened n base (b*1024 + n0)
    const int b  = nBase >> 10;
    const int n0 = nBase & 1023;
    const int eBase = be << 6;
    const bool isQ = (eBase < 256);
    const float* __restrict__ W    = isQ ? wq : wk;
    const float* __restrict__ bias = isQ ? bq : bk;
    float* __restrict__ Og         = isQ ? Qt : Kt;
    const int e0 = isQ ? eBase : (eBase - 256);

    const int sr = tid >> 2;          // 0..63 (n or e index for staging)
    const int sd = (tid & 3) << 2;    // 0,4,8,12

    float acc[4][4];
    #pragma unroll
    for (int i = 0; i < 4; ++i)
        #pragma unroll
        for (int j = 0; j < 4; ++j) acc[i][j] = 0.0f;

    #pragma unroll 1
    for (int dc = 0; dc < 256; dc += 16) {
        const float4 xv = *(const float4*)&x[(size_t)(nBase + sr) * 256 + dc + sd];
        const float4 pv = *(const float4*)&pos[(size_t)(n0 + sr) * 256 + dc + sd];
        const float4 wv = *(const float4*)&W[(size_t)(e0 + sr) * 256 + dc + sd];
        __syncthreads();   // previous compute done reading LDS
        Hs[sd + 0][sr] = xv.x + pv.x;
        Hs[sd + 1][sr] = xv.y + pv.y;
        Hs[sd + 2][sr] = xv.z + pv.z;
        Hs[sd + 3][sr] = xv.w + pv.w;
        Ws[sd + 0][sr] = wv.x;
        Ws[sd + 1][sr] = wv.y;
        Ws[sd + 2][sr] = wv.z;
        Ws[sd + 3][sr] = wv.w;
        __syncthreads();
        #pragma unroll
        for (int d = 0; d < 16; ++d) {
            const float4 ev = *(const float4*)&Ws[d][ty << 2];   // e-dim (rows)
            const float4 nv = *(const float4*)&Hs[d][tx << 2];   // n-dim (cols)
            const float a4[4] = {ev.x, ev.y, ev.z, ev.w};
            const float b4[4] = {nv.x, nv.y, nv.z, nv.w};
            #pragma unroll
            for (int i = 0; i < 4; ++i)
                #pragma unroll
                for (int j = 0; j < 4; ++j)
                    acc[i][j] = fmaf(a4[i], b4[j], acc[i][j]);
        }
    }

    const float4 bv4 = *(const float4*)&bias[e0 + (ty << 2)];
    const float bb[4] = {bv4.x, bv4.y, bv4.z, bv4.w};
    #pragma unroll
    for (int i = 0; i < 4; ++i)
        #pragma unroll
        for (int j = 0; j < 4; ++j) acc[i][j] += bb[i];

    // coalesced transposed stores: row e = e0+4ty+i, cols n0+4tx..+3
    #pragma unroll
    for (int i = 0; i < 4; ++i) {
        float4 o;
        o.x = acc[i][0]; o.y = acc[i][1]; o.z = acc[i][2]; o.w = acc[i][3];
        *(float4*)&Og[(size_t)((b << 8) + e0 + (ty << 2) + i) * 1024 + n0 + (tx << 2)] = o;
    }
}

// ---------------------------------------------------------------------------
// Kernel B v4: scores + softmax + top-16, fused. One WG = (batch b, 32 rows).
// Column-split main loop (wave w owns cols [256w,256w+256), lane owns 4 cols,
// acc[32][4]), barrier-free, 2-deep K register prefetch.
// v4 change vs v3 (VALUBusy 58%, per-iter Q-load latency exposed):
//   Q tile staged ONCE into LDS (Qlds[256][32], d-major). Main-loop Q reads
//   are wave-uniform ds_read_b128 broadcasts (~1-2 clk, latency schedulable)
//   instead of per-iter L2/K$ loads -> load latency off the critical path.
//   Sc epilogue buffer aliases the Q buffer (32 KB LDS total, sync-guarded).
// ---------------------------------------------------------------------------
__global__ __launch_bounds__(256, 2) void adj_topk_kernel(
    const float* __restrict__ Qt, const float* __restrict__ Kt,
    float* __restrict__ out)
{
    __shared__ __align__(16) float SB[8192];      // 32 KB, dual-purpose
    float (*Qlds)[32]  = (float(*)[32])SB;        // [d][r]   main loop
    float (*Sc)[1024]  = (float(*)[1024])SB;      // [rr][m]  epilogue

    const int tid  = threadIdx.x;
    const int lane = tid & 63;
    const int w    = tid >> 6;
    const int b       = blockIdx.x >> 5;
    const int rowBase = (blockIdx.x & 31) << 5;

    // Qt[b][d][rowBase + r]
    const float* __restrict__ Qb = Qt + (size_t)b * (256 * 1024) + rowBase;
    // lane's 4 columns of wave's quarter
    const float* __restrict__ kp = Kt + (size_t)b * (256 * 1024) + (w << 8) + (lane << 2);

    // ---- stage Q tile into LDS: Qlds[d][r] = Qb[d*1024 + r] ----
    // 8 lanes per d-row (float4 each); global: 8-lane groups read 128B chunks;
    // LDS: wave writes 64 lanes x 16B = 1024B linear -> conflict-free.
    {
        const int sd = tid >> 3;              // 0..31 base d
        const int sc = (tid & 7) << 2;        // 0,4,..,28
        #pragma unroll
        for (int p = 0; p < 8; ++p) {
            const int d = sd + (p << 5);
            *(float4*)&Qlds[d][sc] = *(const float4*)&Qb[(size_t)d * 1024 + sc];
        }
    }
    __syncthreads();

    float acc[32][4];
    #pragma unroll
    for (int r = 0; r < 32; ++r)
        #pragma unroll
        for (int c = 0; c < 4; ++c) acc[r][c] = 0.0f;

    // ---- prefetch K for d=0,1 ----
    float4 k0 = *(const float4*)&kp[0];
    float4 k1 = *(const float4*)&kp[1024];

    // ---- main loop: 128 chunks of 2 d-steps, barrier-free ----
    #pragma unroll 2
    for (int d = 0; d < 256; d += 2) {
        const int dn = (d + 2) & 255;          // wrap: final prefetch harmless
        const float4 kn0 = *(const float4*)&kp[(size_t)dn * 1024];
        const float4 kn1 = *(const float4*)&kp[(size_t)(dn + 1) * 1024];

        #pragma unroll
        for (int g = 0; g < 8; ++g) {
            const float4 q0 = *(const float4*)&Qlds[d][g << 2];      // broadcast
            const float4 q1 = *(const float4*)&Qlds[d + 1][g << 2];  // broadcast
            const float q0a[4] = {q0.x, q0.y, q0.z, q0.w};
            const float q1a[4] = {q1.x, q1.y, q1.z, q1.w};
            #pragma unroll
            for (int j = 0; j < 4; ++j) {
                const int r = (g << 2) + j;
                acc[r][0] = fmaf(q0a[j], k0.x, acc[r][0]);
                acc[r][1] = fmaf(q0a[j], k0.y, acc[r][1]);
                acc[r][2] = fmaf(q0a[j], k0.z, acc[r][2]);
                acc[r][3] = fmaf(q0a[j], k0.w, acc[r][3]);
                acc[r][0] = fmaf(q1a[j], k1.x, acc[r][0]);
                acc[r][1] = fmaf(q1a[j], k1.y, acc[r][1]);
                acc[r][2] = fmaf(q1a[j], k1.z, acc[r][2]);
                acc[r][3] = fmaf(q1a[j], k1.w, acc[r][3]);
            }
        }
        k0 = kn0;
        k1 = kn1;
    }

    // ---- epilogue: 4 passes of 8 rows; LDS handoff -> row ownership ----
    const int growBase = b * 1024 + rowBase;

    #pragma unroll
    for (int p = 0; p < 4; ++p) {
        __syncthreads();   // pass 0: all waves done with Qlds; else prior pass
        #pragma unroll
        for (int rr = 0; rr < 8; ++rr) {
            float4 v;
            v.x = acc[(p << 3) + rr][0];
            v.y = acc[(p << 3) + rr][1];
            v.z = acc[(p << 3) + rr][2];
            v.w = acc[(p << 3) + rr][3];
            *(float4*)&Sc[rr][(w << 8) + (lane << 2)] = v;
        }
        __syncthreads();

        // wave w selects rows 2w, 2w+1 of this pass
        #pragma unroll 1
        for (int t = 0; t < 2; ++t) {
            const int srw = (w << 1) + t;          // row within Sc
            float s[16];
            #pragma unroll
            for (int o = 0; o < 4; ++o) {
                const float4 sv = *(const float4*)&Sc[srw][(o << 8) + (lane << 2)];
                s[(o << 2) + 0] = sv.x * 0.0625f;
                s[(o << 2) + 1] = sv.y * 0.0625f;
                s[(o << 2) + 2] = sv.z * 0.0625f;
                s[(o << 2) + 3] = sv.w * 0.0625f;
            }

            // row max (wave butterfly)
            float mx = s[0];
            #pragma unroll
            for (int i = 1; i < 16; ++i) mx = fmaxf(mx, s[i]);
            #pragma unroll
            for (int off = 32; off > 0; off >>= 1)
                mx = fmaxf(mx, __shfl_xor(mx, off));

            // softmax denominator
            float ls = 0.f;
            #pragma unroll
            for (int i = 0; i < 16; ++i) ls += __expf(s[i] - mx);
            #pragma unroll
            for (int off = 32; off > 0; off >>= 1)
                ls += __shfl_xor(ls, off);
            const float rZ = 1.0f / ls;

            // top-16 extraction on a destructible copy; winners -> bitmask
            float wv[16];
            #pragma unroll
            for (int i = 0; i < 16; ++i) wv[i] = s[i];
            unsigned mask = 0u;

            #pragma unroll 1
            for (int j = 0; j < KNNK; ++j) {
                float bv  = wv[0];
                int   bsi = 0;
                #pragma unroll
                for (int i = 1; i < 16; ++i) {
                    const bool c = wv[i] > bv;   // strict >, ascending slot scan
                    bv  = c ? wv[i] : bv;
                    bsi = c ? i     : bsi;
                }
                const int bmi = ((bsi >> 2) << 8) + (lane << 2) + (bsi & 3);
                const unsigned ub   = __float_as_uint(bv);
                const unsigned mono = ub ^ (unsigned)(((int)ub >> 31) | 0x80000000);
                const unsigned long long key =
                    ((unsigned long long)mono << 32) | (unsigned)(~bmi);
                unsigned long long gk = key;
                #pragma unroll
                for (int off = 32; off > 0; off >>= 1) {
                    const unsigned long long o = __shfl_xor(gk, off);
                    gk = (o > gk) ? o : gk;
                }
                if (key == gk) {                 // unique winner lane
                    mask |= (1u << bsi);
                    #pragma unroll
                    for (int i = 0; i < 16; ++i)
                        wv[i] = (i == bsi) ? -__builtin_inff() : wv[i];
                }
            }

            // single full-coverage coalesced write pass for this row
            float* orow = out + ((size_t)(growBase + (p << 3) + srw)) * 1024;
            #pragma unroll
            for (int o = 0; o < 4; ++o) {
                float4 v;
                v.x = ((mask >> ((o << 2) + 0)) & 1u) ? __expf(s[(o << 2) + 0] - mx) * rZ : 0.f;
                v.y = ((mask >> ((o << 2) + 1)) & 1u) ? __expf(s[(o << 2) + 1] - mx) * rZ : 0.f;
                v.z = ((mask >> ((o << 2) + 2)) & 1u) ? __expf(s[(o << 2) + 2] - mx) * rZ : 0.f;
                v.w = ((mask >> ((o << 2) + 3)) & 1u) ? __expf(s[(o << 2) + 3] - mx) * rZ : 0.f;
                *(float4*)&orow[(lane << 2) + (o << 8)] = v;
            }
        }
    }
}

extern "C" void kernel_launch(void* const* d_in, const int* in_sizes, int n_in,
                              void* d_out, int out_size, void* d_ws, size_t ws_size,
                              hipStream_t stream)
{
    const float* x   = (const float*)d_in[0];
    const float* pos = (const float*)d_in[1];
    const float* wq  = (const float*)d_in[2];
    const float* bq  = (const float*)d_in[3];
    const float* wk  = (const float*)d_in[4];
    const float* bk  = (const float*)d_in[5];
    float* out = (float*)d_out;

    float* Qt = (float*)d_ws;                    // 32 MB: [B, 256, 1024]
    float* Kt = Qt + (size_t)NB * NN * ND;       // 32 MB: [B, 256, 1024]

    proj_kernel<<<dim3(4096), dim3(256), 0, stream>>>(x, pos, wq, bq, wk, bk, Qt, Kt);
    adj_topk_kernel<<<dim3(1024), dim3(256), 0, stream>>>(Qt, Kt, out);
}

// Round 5
// 485.450 us; speedup vs baseline: 1.0840x; 1.0840x over previous
//
#include <hip/hip_runtime.h>
#include <cstdint>
#include <cstddef>

#define NB 32
#define NN 1024
#define ND 256
#define KNNK 16

// ---------------------------------------------------------------------------
// Kernel A v3: fused positional-add + dual projection GEMM, TRANSPOSED out:
//   Qt [B, 256, 1024], Kt [B, 256, 1024]   (out[e][n] = sum_d h[n][d] w[e][d])
// Tile: 64 e x 64 n, 256 threads, 4x4 microtile. (measured ~90 us)
// ---------------------------------------------------------------------------
__global__ __launch_bounds__(256) void proj_kernel(
    const float* __restrict__ x, const float* __restrict__ pos,
    const float* __restrict__ wq, const float* __restrict__ bq,
    const float* __restrict__ wk, const float* __restrict__ bk,
    float* __restrict__ Qt, float* __restrict__ Kt)
{
    __shared__ __align__(16) float Hs[16][64];   // [d][n_local]
    __shared__ __align__(16) float Ws[16][64];   // [d][e_local]

    const int tid = threadIdx.x;
    const int tx = tid & 15;          // n microtile index
    const int ty = tid >> 4;          // e microtile index
    const int bm = blockIdx.x >> 3;   // 0..511 n tiles (b*16 + ntile)
    const int be = blockIdx.x & 7;    // 0..7 e tiles (0-3 -> Q, 4-7 -> K)
    const int nBase = bm << 6;        // global flattened n base (b*1024 + n0)
    const int b  = nBase >> 10;
    const int n0 = nBase & 1023;
    const int eBase = be << 6;
    const bool isQ = (eBase < 256);
    const float* __restrict__ W    = isQ ? wq : wk;
    const float* __restrict__ bias = isQ ? bq : bk;
    float* __restrict__ Og         = isQ ? Qt : Kt;
    const int e0 = isQ ? eBase : (eBase - 256);

    const int sr = tid >> 2;          // 0..63 (n or e index for staging)
    const int sd = (tid & 3) << 2;    // 0,4,8,12

    float acc[4][4];
    #pragma unroll
    for (int i = 0; i < 4; ++i)
        #pragma unroll
        for (int j = 0; j < 4; ++j) acc[i][j] = 0.0f;

    #pragma unroll 1
    for (int dc = 0; dc < 256; dc += 16) {
        const float4 xv = *(const float4*)&x[(size_t)(nBase + sr) * 256 + dc + sd];
        const float4 pv = *(const float4*)&pos[(size_t)(n0 + sr) * 256 + dc + sd];
        const float4 wv = *(const float4*)&W[(size_t)(e0 + sr) * 256 + dc + sd];
        __syncthreads();   // previous compute done reading LDS
        Hs[sd + 0][sr] = xv.x + pv.x;
        Hs[sd + 1][sr] = xv.y + pv.y;
        Hs[sd + 2][sr] = xv.z + pv.z;
        Hs[sd + 3][sr] = xv.w + pv.w;
        Ws[sd + 0][sr] = wv.x;
        Ws[sd + 1][sr] = wv.y;
        Ws[sd + 2][sr] = wv.z;
        Ws[sd + 3][sr] = wv.w;
        __syncthreads();
        #pragma unroll
        for (int d = 0; d < 16; ++d) {
            const float4 ev = *(const float4*)&Ws[d][ty << 2];   // e-dim (rows)
            const float4 nv = *(const float4*)&Hs[d][tx << 2];   // n-dim (cols)
            const float a4[4] = {ev.x, ev.y, ev.z, ev.w};
            const float b4[4] = {nv.x, nv.y, nv.z, nv.w};
            #pragma unroll
            for (int i = 0; i < 4; ++i)
                #pragma unroll
                for (int j = 0; j < 4; ++j)
                    acc[i][j] = fmaf(a4[i], b4[j], acc[i][j]);
        }
    }

    const float4 bv4 = *(const float4*)&bias[e0 + (ty << 2)];
    const float bb[4] = {bv4.x, bv4.y, bv4.z, bv4.w};
    #pragma unroll
    for (int i = 0; i < 4; ++i)
        #pragma unroll
        for (int j = 0; j < 4; ++j) acc[i][j] += bb[i];

    // coalesced transposed stores: row e = e0+4ty+i, cols n0+4tx..+3
    #pragma unroll
    for (int i = 0; i < 4; ++i) {
        float4 o;
        o.x = acc[i][0]; o.y = acc[i][1]; o.z = acc[i][2]; o.w = acc[i][3];
        *(float4*)&Og[(size_t)((b << 8) + e0 + (ty << 2) + i) * 1024 + n0 + (tx << 2)] = o;
    }
}

// ---------------------------------------------------------------------------
// Kernel B v5: scores + softmax + top-16, fused. One WG = (batch b, 32 rows),
// 512 threads = 8 waves: wave = (row-half rh, col-quarter cq).
// v5 change vs v4 (AGPR-move tax + 2 waves/SIMD):
//   acc[16][4] = 64 VGPRs -> whole wave state fits true VGPRs under the
//   __launch_bounds__(512,4) cap of 128 -> no v_accvgpr moves, 4 waves/SIMD.
//   Q read with wave-uniform global loads (v3's fastest scheme; readfirstlane
//   guarantees scalarization). K: 2-deep register prefetch, barrier-free loop.
//   Epilogue: LDS handoff (32 KB), 1 row per wave per pass, bit-identical
//   selection + single coalesced full-coverage write pass.
// ---------------------------------------------------------------------------
__global__ __launch_bounds__(512, 4) void adj_topk_kernel(
    const float* __restrict__ Qt, const float* __restrict__ Kt,
    float* __restrict__ out)
{
    __shared__ __align__(16) float Sc[8][1024];   // 32 KB

    const int tid  = threadIdx.x;
    const int lane = tid & 63;
    const int w    = __builtin_amdgcn_readfirstlane(tid >> 6);  // 0..7
    const int rh   = w >> 2;          // row half: 16 rows
    const int cq   = w & 3;           // col quarter: 256 cols
    const int b       = blockIdx.x >> 5;
    const int rowBase = (blockIdx.x & 31) << 5;

    // Qt[b][d][rowBase + rh*16 + r]  (wave-uniform -> s_load)
    const float* __restrict__ Qb = Qt + (size_t)b * (256 * 1024) + rowBase + (rh << 4);
    // lane's 4 columns of wave's quarter
    const float* __restrict__ kp = Kt + (size_t)b * (256 * 1024) + (cq << 8) + (lane << 2);

    float acc[16][4];
    #pragma unroll
    for (int r = 0; r < 16; ++r)
        #pragma unroll
        for (int c = 0; c < 4; ++c) acc[r][c] = 0.0f;

    // ---- prefetch K for d=0,1 ----
    float4 k0 = *(const float4*)&kp[0];
    float4 k1 = *(const float4*)&kp[1024];

    // ---- main loop: 128 chunks of 2 d-steps, barrier-free ----
    #pragma unroll 2
    for (int d = 0; d < 256; d += 2) {
        const int dn = (d + 2) & 255;          // wrap: final prefetch harmless
        const float4 kn0 = *(const float4*)&kp[(size_t)dn * 1024];
        const float4 kn1 = *(const float4*)&kp[(size_t)(dn + 1) * 1024];

        const float* __restrict__ qrow0 = Qb + (size_t)d * 1024;
        const float* __restrict__ qrow1 = qrow0 + 1024;

        #pragma unroll
        for (int g = 0; g < 4; ++g) {
            const float4 q0 = *(const float4*)(qrow0 + (g << 2));  // uniform
            const float4 q1 = *(const float4*)(qrow1 + (g << 2));  // uniform
            const float q0a[4] = {q0.x, q0.y, q0.z, q0.w};
            const float q1a[4] = {q1.x, q1.y, q1.z, q1.w};
            #pragma unroll
            for (int j = 0; j < 4; ++j) {
                const int r = (g << 2) + j;
                acc[r][0] = fmaf(q0a[j], k0.x, acc[r][0]);
                acc[r][1] = fmaf(q0a[j], k0.y, acc[r][1]);
                acc[r][2] = fmaf(q0a[j], k0.z, acc[r][2]);
                acc[r][3] = fmaf(q0a[j], k0.w, acc[r][3]);
                acc[r][0] = fmaf(q1a[j], k1.x, acc[r][0]);
                acc[r][1] = fmaf(q1a[j], k1.y, acc[r][1]);
                acc[r][2] = fmaf(q1a[j], k1.z, acc[r][2]);
                acc[r][3] = fmaf(q1a[j], k1.w, acc[r][3]);
            }
        }
        k0 = kn0;
        k1 = kn1;
    }

    // ---- epilogue: 4 passes of 8 rows; LDS handoff -> row ownership ----
    const int growBase = b * 1024 + rowBase;

    #pragma unroll 1
    for (int p = 0; p < 4; ++p) {
        __syncthreads();            // prior pass reads (or main loop) complete
        if (rh == (p >> 1)) {       // wave-uniform branch
            const int lr0 = (p & 1) << 3;
            #pragma unroll
            for (int rr = 0; rr < 8; ++rr) {
                float4 v;
                v.x = acc[lr0 + rr][0];
                v.y = acc[lr0 + rr][1];
                v.z = acc[lr0 + rr][2];
                v.w = acc[lr0 + rr][3];
                *(float4*)&Sc[rr][(cq << 8) + (lane << 2)] = v;
            }
        }
        __syncthreads();

        // wave w selects row (p*8 + w) of the block
        float s[16];
        #pragma unroll
        for (int o = 0; o < 4; ++o) {
            const float4 sv = *(const float4*)&Sc[w][(o << 8) + (lane << 2)];
            s[(o << 2) + 0] = sv.x * 0.0625f;
            s[(o << 2) + 1] = sv.y * 0.0625f;
            s[(o << 2) + 2] = sv.z * 0.0625f;
            s[(o << 2) + 3] = sv.w * 0.0625f;
        }

        // row max (wave butterfly)
        float mx = s[0];
        #pragma unroll
        for (int i = 1; i < 16; ++i) mx = fmaxf(mx, s[i]);
        #pragma unroll
        for (int off = 32; off > 0; off >>= 1)
            mx = fmaxf(mx, __shfl_xor(mx, off));

        // softmax denominator
        float ls = 0.f;
        #pragma unroll
        for (int i = 0; i < 16; ++i) ls += __expf(s[i] - mx);
        #pragma unroll
        for (int off = 32; off > 0; off >>= 1)
            ls += __shfl_xor(ls, off);
        const float rZ = 1.0f / ls;

        // top-16 extraction on a destructible copy; winners -> bitmask
        float wv[16];
        #pragma unroll
        for (int i = 0; i < 16; ++i) wv[i] = s[i];
        unsigned mask = 0u;

        #pragma unroll 1
        for (int j = 0; j < KNNK; ++j) {
            float bv  = wv[0];
            int   bsi = 0;
            #pragma unroll
            for (int i = 1; i < 16; ++i) {
                const bool c = wv[i] > bv;   // strict >, ascending slot scan
                bv  = c ? wv[i] : bv;
                bsi = c ? i     : bsi;
            }
            const int bmi = ((bsi >> 2) << 8) + (lane << 2) + (bsi & 3);
            const unsigned ub   = __float_as_uint(bv);
            const unsigned mono = ub ^ (unsigned)(((int)ub >> 31) | 0x80000000);
            const unsigned long long key =
                ((unsigned long long)mono << 32) | (unsigned)(~bmi);
            unsigned long long gk = key;
            #pragma unroll
            for (int off = 32; off > 0; off >>= 1) {
                const unsigned long long o = __shfl_xor(gk, off);
                gk = (o > gk) ? o : gk;
            }
            if (key == gk) {                 // unique winner lane
                mask |= (1u << bsi);
                #pragma unroll
                for (int i = 0; i < 16; ++i)
                    wv[i] = (i == bsi) ? -__builtin_inff() : wv[i];
            }
        }

        // single full-coverage coalesced write pass for this row
        float* orow = out + ((size_t)(growBase + (p << 3) + w)) * 1024;
        #pragma unroll
        for (int o = 0; o < 4; ++o) {
            float4 v;
            v.x = ((mask >> ((o << 2) + 0)) & 1u) ? __expf(s[(o << 2) + 0] - mx) * rZ : 0.f;
            v.y = ((mask >> ((o << 2) + 1)) & 1u) ? __expf(s[(o << 2) + 1] - mx) * rZ : 0.f;
            v.z = ((mask >> ((o << 2) + 2)) & 1u) ? __expf(s[(o << 2) + 2] - mx) * rZ : 0.f;
            v.w = ((mask >> ((o << 2) + 3)) & 1u) ? __expf(s[(o << 2) + 3] - mx) * rZ : 0.f;
            *(float4*)&orow[(lane << 2) + (o << 8)] = v;
        }
    }
}

extern "C" void kernel_launch(void* const* d_in, const int* in_sizes, int n_in,
                              void* d_out, int out_size, void* d_ws, size_t ws_size,
                              hipStream_t stream)
{
    const float* x   = (const float*)d_in[0];
    const float* pos = (const float*)d_in[1];
    const float* wq  = (const float*)d_in[2];
    const float* bq  = (const float*)d_in[3];
    const float* wk  = (const float*)d_in[4];
    const float* bk  = (const float*)d_in[5];
    float* out = (float*)d_out;

    float* Qt = (float*)d_ws;                    // 32 MB: [B, 256, 1024]
    float* Kt = Qt + (size_t)NB * NN * ND;       // 32 MB: [B, 256, 1024]

    proj_kernel<<<dim3(4096), dim3(256), 0, stream>>>(x, pos, wq, bq, wk, bk, Qt, Kt);
    adj_topk_kernel<<<dim3(1024), dim3(512), 0, stream>>>(Qt, Kt, out);
}

// Round 6
// 457.207 us; speedup vs baseline: 1.1509x; 1.0618x over previous
//
#include <hip/hip_runtime.h>
#include <cstdint>
#include <cstddef>

#define NB 32
#define NN 1024
#define ND 256
#define KNNK 16

// ---------------------------------------------------------------------------
// Kernel A v3: fused positional-add + dual projection GEMM, TRANSPOSED out:
//   Qt [B, 256, 1024], Kt [B, 256, 1024]   (out[e][n] = sum_d h[n][d] w[e][d])
// Tile: 64 e x 64 n, 256 threads, 4x4 microtile. (measured ~85 us)
// ---------------------------------------------------------------------------
__global__ __launch_bounds__(256) void proj_kernel(
    const float* __restrict__ x, const float* __restrict__ pos,
    const float* __restrict__ wq, const float* __restrict__ bq,
    const float* __restrict__ wk, const float* __restrict__ bk,
    float* __restrict__ Qt, float* __restrict__ Kt)
{
    __shared__ __align__(16) float Hs[16][64];   // [d][n_local]
    __shared__ __align__(16) float Ws[16][64];   // [d][e_local]

    const int tid = threadIdx.x;
    const int tx = tid & 15;          // n microtile index
    const int ty = tid >> 4;          // e microtile index
    const int bm = blockIdx.x >> 3;   // 0..511 n tiles (b*16 + ntile)
    const int be = blockIdx.x & 7;    // 0..7 e tiles (0-3 -> Q, 4-7 -> K)
    const int nBase = bm << 6;        // global flattened n base (b*1024 + n0)
    const int b  = nBase >> 10;
    const int n0 = nBase & 1023;
    const int eBase = be << 6;
    const bool isQ = (eBase < 256);
    const float* __restrict__ W    = isQ ? wq : wk;
    const float* __restrict__ bias = isQ ? bq : bk;
    float* __restrict__ Og         = isQ ? Qt : Kt;
    const int e0 = isQ ? eBase : (eBase - 256);

    const int sr = tid >> 2;          // 0..63 (n or e index for staging)
    const int sd = (tid & 3) << 2;    // 0,4,8,12

    float acc[4][4];
    #pragma unroll
    for (int i = 0; i < 4; ++i)
        #pragma unroll
        for (int j = 0; j < 4; ++j) acc[i][j] = 0.0f;

    #pragma unroll 1
    for (int dc = 0; dc < 256; dc += 16) {
        const float4 xv = *(const float4*)&x[(size_t)(nBase + sr) * 256 + dc + sd];
        const float4 pv = *(const float4*)&pos[(size_t)(n0 + sr) * 256 + dc + sd];
        const float4 wv = *(const float4*)&W[(size_t)(e0 + sr) * 256 + dc + sd];
        __syncthreads();   // previous compute done reading LDS
        Hs[sd + 0][sr] = xv.x + pv.x;
        Hs[sd + 1][sr] = xv.y + pv.y;
        Hs[sd + 2][sr] = xv.z + pv.z;
        Hs[sd + 3][sr] = xv.w + pv.w;
        Ws[sd + 0][sr] = wv.x;
        Ws[sd + 1][sr] = wv.y;
        Ws[sd + 2][sr] = wv.z;
        Ws[sd + 3][sr] = wv.w;
        __syncthreads();
        #pragma unroll
        for (int d = 0; d < 16; ++d) {
            const float4 ev = *(const float4*)&Ws[d][ty << 2];   // e-dim (rows)
            const float4 nv = *(const float4*)&Hs[d][tx << 2];   // n-dim (cols)
            const float a4[4] = {ev.x, ev.y, ev.z, ev.w};
            const float b4[4] = {nv.x, nv.y, nv.z, nv.w};
            #pragma unroll
            for (int i = 0; i < 4; ++i)
                #pragma unroll
                for (int j = 0; j < 4; ++j)
                    acc[i][j] = fmaf(a4[i], b4[j], acc[i][j]);
        }
    }

    const float4 bv4 = *(const float4*)&bias[e0 + (ty << 2)];
    const float bb[4] = {bv4.x, bv4.y, bv4.z, bv4.w};
    #pragma unroll
    for (int i = 0; i < 4; ++i)
        #pragma unroll
        for (int j = 0; j < 4; ++j) acc[i][j] += bb[i];

    // coalesced transposed stores: row e = e0+4ty+i, cols n0+4tx..+3
    #pragma unroll
    for (int i = 0; i < 4; ++i) {
        float4 o;
        o.x = acc[i][0]; o.y = acc[i][1]; o.z = acc[i][2]; o.w = acc[i][3];
        *(float4*)&Og[(size_t)((b << 8) + e0 + (ty << 2) + i) * 1024 + n0 + (tx << 2)] = o;
    }
}

// ---------------------------------------------------------------------------
// Kernel B v6: scores + softmax + top-16, fused. One WG = (batch b, 32 rows),
// 512 threads = 8 waves; wave w owns col slice [128w, 128w+128), lane owns 2
// adjacent cols, acc[32][2] (all 32 rows per wave -> no duplicate K reads).
// v6 changes vs v5 (L2 thrash: FETCH 305MB, VALUBusy pinned 58%):
//  - XCD-batch swizzle: bid=(orig&7)*128+(orig>>3) -> each XCD works on
//    contiguous batches; resident set ~4MB = per-XCD L2. Kills HBM re-fetch.
//  - 8-way col split: block K L2 demand 1MB (was 2MB, rh-duplicated).
//  - Epilogue: 2 passes x 16 rows (Sc 64KB), 2 rows per wave processed
//    CONCURRENTLY (selection round logic verbatim, paired) -> latency chains
//    of the 16 extraction rounds overlap.
// ---------------------------------------------------------------------------
__global__ __launch_bounds__(512, 4) void adj_topk_kernel(
    const float* __restrict__ Qt, const float* __restrict__ Kt,
    float* __restrict__ out)
{
    __shared__ __align__(16) float Sc[16][1024];   // 64 KB

    const int tid  = threadIdx.x;
    const int lane = tid & 63;
    const int w    = __builtin_amdgcn_readfirstlane(tid >> 6);  // 0..7
    const int bid  = ((blockIdx.x & 7) << 7) + (blockIdx.x >> 3);  // XCD swizzle
    const int b       = bid >> 5;
    const int rowBase = (bid & 31) << 5;

    // Qt[b][d][rowBase + r]  (wave-uniform -> s_load)
    const float* __restrict__ Qb = Qt + (size_t)b * (256 * 1024) + rowBase;
    // lane's 2 adjacent columns of wave's 128-col slice
    const float* __restrict__ kp = Kt + (size_t)b * (256 * 1024) + (w << 7) + (lane << 1);

    float acc[32][2];
    #pragma unroll
    for (int r = 0; r < 32; ++r) {
        acc[r][0] = 0.0f;
        acc[r][1] = 0.0f;
    }

    // ---- prefetch K for d=0,1 ----
    float2 k0 = *(const float2*)&kp[0];
    float2 k1 = *(const float2*)&kp[1024];

    // ---- main loop: 128 chunks of 2 d-steps, barrier-free ----
    #pragma unroll 2
    for (int d = 0; d < 256; d += 2) {
        const int dn = (d + 2) & 255;          // wrap: final prefetch harmless
        const float2 kn0 = *(const float2*)&kp[(size_t)dn * 1024];
        const float2 kn1 = *(const float2*)&kp[(size_t)(dn + 1) * 1024];

        const float* __restrict__ qrow0 = Qb + (size_t)d * 1024;
        const float* __restrict__ qrow1 = qrow0 + 1024;

        #pragma unroll
        for (int g = 0; g < 8; ++g) {
            const float4 q0 = *(const float4*)(qrow0 + (g << 2));  // uniform
            const float4 q1 = *(const float4*)(qrow1 + (g << 2));  // uniform
            const float q0a[4] = {q0.x, q0.y, q0.z, q0.w};
            const float q1a[4] = {q1.x, q1.y, q1.z, q1.w};
            #pragma unroll
            for (int j = 0; j < 4; ++j) {
                const int r = (g << 2) + j;
                acc[r][0] = fmaf(q0a[j], k0.x, acc[r][0]);
                acc[r][1] = fmaf(q0a[j], k0.y, acc[r][1]);
                acc[r][0] = fmaf(q1a[j], k1.x, acc[r][0]);
                acc[r][1] = fmaf(q1a[j], k1.y, acc[r][1]);
            }
        }
        k0 = kn0;
        k1 = kn1;
    }

    // ---- epilogue: 2 passes of 16 rows; 2 rows per wave, interleaved ----
    const int growBase = b * 1024 + rowBase;

    #pragma unroll 1
    for (int p = 0; p < 2; ++p) {
        __syncthreads();            // prior pass reads (or main loop) complete
        #pragma unroll
        for (int rr = 0; rr < 16; ++rr) {
            float2 v;
            v.x = acc[(p << 4) + rr][0];
            v.y = acc[(p << 4) + rr][1];
            *(float2*)&Sc[rr][(w << 7) + (lane << 1)] = v;
        }
        __syncthreads();

        // wave w owns rows 2w, 2w+1 of this pass; process both concurrently
        float s[2][16];
        #pragma unroll
        for (int t = 0; t < 2; ++t) {
            const int srw = (w << 1) + t;
            #pragma unroll
            for (int o = 0; o < 4; ++o) {
                const float4 sv = *(const float4*)&Sc[srw][(o << 8) + (lane << 2)];
                s[t][(o << 2) + 0] = sv.x * 0.0625f;
                s[t][(o << 2) + 1] = sv.y * 0.0625f;
                s[t][(o << 2) + 2] = sv.z * 0.0625f;
                s[t][(o << 2) + 3] = sv.w * 0.0625f;
            }
        }

        // row max (wave butterfly), both rows interleaved
        float mx[2];
        #pragma unroll
        for (int t = 0; t < 2; ++t) {
            mx[t] = s[t][0];
            #pragma unroll
            for (int i = 1; i < 16; ++i) mx[t] = fmaxf(mx[t], s[t][i]);
        }
        #pragma unroll
        for (int off = 32; off > 0; off >>= 1) {
            mx[0] = fmaxf(mx[0], __shfl_xor(mx[0], off));
            mx[1] = fmaxf(mx[1], __shfl_xor(mx[1], off));
        }

        // softmax denominator, both rows interleaved
        float ls[2] = {0.f, 0.f};
        #pragma unroll
        for (int t = 0; t < 2; ++t)
            #pragma unroll
            for (int i = 0; i < 16; ++i) ls[t] += __expf(s[t][i] - mx[t]);
        #pragma unroll
        for (int off = 32; off > 0; off >>= 1) {
            ls[0] += __shfl_xor(ls[0], off);
            ls[1] += __shfl_xor(ls[1], off);
        }
        const float rZ0 = 1.0f / ls[0];
        const float rZ1 = 1.0f / ls[1];

        // top-16 extraction (both rows concurrently); winners -> bitmask
        float wv[2][16];
        #pragma unroll
        for (int t = 0; t < 2; ++t)
            #pragma unroll
            for (int i = 0; i < 16; ++i) wv[t][i] = s[t][i];
        unsigned mask[2] = {0u, 0u};

        #pragma unroll 1
        for (int j = 0; j < KNNK; ++j) {
            unsigned long long key[2], gk[2];
            int bsi[2];
            #pragma unroll
            for (int t = 0; t < 2; ++t) {
                float bv  = wv[t][0];
                int   bi  = 0;
                #pragma unroll
                for (int i = 1; i < 16; ++i) {
                    const bool c = wv[t][i] > bv;   // strict >, ascending scan
                    bv = c ? wv[t][i] : bv;
                    bi = c ? i        : bi;
                }
                bsi[t] = bi;
                const int bmi = ((bi >> 2) << 8) + (lane << 2) + (bi & 3);
                const unsigned ub   = __float_as_uint(bv);
                const unsigned mono = ub ^ (unsigned)(((int)ub >> 31) | 0x80000000);
                key[t] = ((unsigned long long)mono << 32) | (unsigned)(~bmi);
                gk[t]  = key[t];
            }
            #pragma unroll
            for (int off = 32; off > 0; off >>= 1) {
                const unsigned long long o0 = __shfl_xor(gk[0], off);
                const unsigned long long o1 = __shfl_xor(gk[1], off);
                gk[0] = (o0 > gk[0]) ? o0 : gk[0];
                gk[1] = (o1 > gk[1]) ? o1 : gk[1];
            }
            #pragma unroll
            for (int t = 0; t < 2; ++t) {
                if (key[t] == gk[t]) {            // unique winner lane
                    mask[t] |= (1u << bsi[t]);
                    #pragma unroll
                    for (int i = 0; i < 16; ++i)
                        wv[t][i] = (i == bsi[t]) ? -__builtin_inff() : wv[t][i];
                }
            }
        }

        // single full-coverage coalesced write pass, one row at a time
        #pragma unroll
        for (int t = 0; t < 2; ++t) {
            const float mxx = mx[t];
            const float rZ  = t ? rZ1 : rZ0;
            float* orow = out + ((size_t)(growBase + (p << 4) + (w << 1) + t)) * 1024;
            #pragma unroll
            for (int o = 0; o < 4; ++o) {
                float4 v;
                v.x = ((mask[t] >> ((o << 2) + 0)) & 1u) ? __expf(s[t][(o << 2) + 0] - mxx) * rZ : 0.f;
                v.y = ((mask[t] >> ((o << 2) + 1)) & 1u) ? __expf(s[t][(o << 2) + 1] - mxx) * rZ : 0.f;
                v.z = ((mask[t] >> ((o << 2) + 2)) & 1u) ? __expf(s[t][(o << 2) + 2] - mxx) * rZ : 0.f;
                v.w = ((mask[t] >> ((o << 2) + 3)) & 1u) ? __expf(s[t][(o << 2) + 3] - mxx) * rZ : 0.f;
                *(float4*)&orow[(lane << 2) + (o << 8)] = v;
            }
        }
    }
}

extern "C" void kernel_launch(void* const* d_in, const int* in_sizes, int n_in,
                              void* d_out, int out_size, void* d_ws, size_t ws_size,
                              hipStream_t stream)
{
    const float* x   = (const float*)d_in[0];
    const float* pos = (const float*)d_in[1];
    const float* wq  = (const float*)d_in[2];
    const float* bq  = (const float*)d_in[3];
    const float* wk  = (const float*)d_in[4];
    const float* bk  = (const float*)d_in[5];
    float* out = (float*)d_out;

    float* Qt = (float*)d_ws;                    // 32 MB: [B, 256, 1024]
    float* Kt = Qt + (size_t)NB * NN * ND;       // 32 MB: [B, 256, 1024]

    proj_kernel<<<dim3(4096), dim3(256), 0, stream>>>(x, pos, wq, bq, wk, bk, Qt, Kt);
    adj_topk_kernel<<<dim3(1024), dim3(512), 0, stream>>>(Qt, Kt, out);
}